// Round 7
// baseline (702.430 us; speedup 1.0000x reference)
//
#include <hip/hip_runtime.h>
#include <cfloat>

#define B_    4
#define SNIP  8
#define CCH   256
#define HW    784
#define THW   6272      // SNIP*HW
#define NROWS 25088     // B_*THW
#define TOPK  5

typedef _Float16 f16;
typedef f16   half8  __attribute__((ext_vector_type(8)));
typedef f16   half4  __attribute__((ext_vector_type(4)));
typedef float f32x4  __attribute__((ext_vector_type(4)));
typedef float f32x16 __attribute__((ext_vector_type(16)));

// ---------------------------------------------------------------- utilities
__device__ __forceinline__ void ins5(float key, int idx, float tv[TOPK], int ti[TOPK]) {
    if (key > tv[4]) {
        if (key > tv[2]) {
            if (key > tv[1]) {
                tv[4] = tv[3]; ti[4] = ti[3];
                tv[3] = tv[2]; ti[3] = ti[2];
                tv[2] = tv[1]; ti[2] = ti[1];
                if (key > tv[0]) { tv[1] = tv[0]; ti[1] = ti[0]; tv[0] = key; ti[0] = idx; }
                else             { tv[1] = key;  ti[1] = idx; }
            } else {
                tv[4] = tv[3]; ti[4] = ti[3];
                tv[3] = tv[2]; ti[3] = ti[2];
                tv[2] = key;   ti[2] = idx;
            }
        } else {
            if (key > tv[3]) { tv[4] = tv[3]; ti[4] = ti[3]; tv[3] = key; ti[3] = idx; }
            else             { tv[4] = key;  ti[4] = idx; }
        }
    }
}

__device__ __forceinline__ void async16(const void* g, void* l) {
    __builtin_amdgcn_global_load_lds(
        (const __attribute__((address_space(1))) void*)g,
        (__attribute__((address_space(3))) void*)l, 16, 0, 0);
}

// ------------------------------------------------- 1. fused transpose + rownorm + f16 split
__global__ __launch_bounds__(256)
void transpose_norm_split_kernel(const float* __restrict__ x, f16* __restrict__ Xs,
                                 float* __restrict__ rinv) {
    __shared__ float T[256][33];
    const int bs = blockIdx.x;
    const int p0 = blockIdx.y * 32;
    const int b = bs >> 3, f = bs & 7;
    const int tid = threadIdx.x;

    const int pl = tid & 31, ch = tid >> 5;
    const int p = p0 + pl;
    if (p < HW) {
#pragma unroll
        for (int cc = 0; cc < 32; ++cc) {
            const int c = cc * 8 + ch;
            T[c][pl] = x[((size_t)bs * CCH + c) * HW + p];
        }
    }
    __syncthreads();

    const int rloc = tid >> 3, k = tid & 7;
    const int gp = p0 + rloc;
    const size_t trow = (size_t)b * THW + (size_t)f * HW + gp;

    float s = 0.0f;
    if (gp < HW) {
#pragma unroll
        for (int j = 0; j < 32; ++j) {
            const float v = T[k * 32 + j][rloc];
            s += v * v;
        }
    }
    s += __shfl_xor(s, 1, 64);
    s += __shfl_xor(s, 2, 64);
    s += __shfl_xor(s, 4, 64);
    if (k == 0 && gp < HW) rinv[trow] = 1.0f / sqrtf(s);

    if (gp < HW) {
#pragma unroll
        for (int q = 0; q < 4; ++q) {
            half8 hv, lv;
#pragma unroll
            for (int j = 0; j < 8; ++j) {
                const float v = T[k * 32 + q * 8 + j][rloc];
                const f16 h = (f16)v;
                hv[j] = h;
                lv[j] = (f16)(v - (float)h);
            }
            *(half8*)(Xs + trow * 512 + k * 32 + q * 8) = hv;
            *(half8*)(Xs + trow * 512 + 256 + k * 32 + q * 8) = lv;
        }
    }
}

// ------------------------------------------------- 2. MFMA gram + partial top-5 (32x32x16)
// grid (49, 7, 4). Per block: 128-col block, 7 row-tiles of 128, virtual K=768
// (f16 split: segments A=[hi,lo,hi], B=[hi,hi,lo]). Staging identical to the
// measured r2/r6 kernel; inner MFMA switched to 32x32x16 (2x2 tiles/wave).
__global__ __launch_bounds__(256, 3)
void gram_mfma_kernel(const f16* __restrict__ Xs, const float* __restrict__ rinv,
                      float* __restrict__ pval, int* __restrict__ pidx) {
    __shared__ __align__(16) char smem[32768];   // staging 32KB | merge 15KB (reused)
    f16* As = (f16*)smem;                 // [128][64] halves, unit-swizzled
    f16* Bs = As + 8192;

    const int tid = threadIdx.x;
    const int lane = tid & 63, wid = tid >> 6;
    const int wr = (wid >> 1) * 64, wc = (wid & 1) * 64;
    const int l31 = lane & 31, h = lane >> 5;
    const int rsw = l31 & 7;              // frag-row XOR key (wr,32i are mult of 8)
    const int b = blockIdx.z;
    const int j0 = blockIdx.x * 128;
    const int rg = blockIdx.y;
    const size_t bbase = (size_t)b * THW;
    const f16* Xb = Xs + bbase * 512;
    const float* rv = rinv + bbase;

    // staging lane map: row within pass, swizzled 16B-unit within row
    const int srow = tid >> 3;
    const int skk = (((tid & 7) ^ (srow & 7)) * 8);   // halves

    int fj[2];
#pragma unroll
    for (int j = 0; j < 2; ++j) fj[j] = (j0 + wc + 32 * j + l31) / HW;

    float tv[2][TOPK];
    int   ti[2][TOPK];
#pragma unroll
    for (int j = 0; j < 2; ++j)
#pragma unroll
        for (int s = 0; s < TOPK; ++s) { tv[j][s] = -FLT_MAX; ti[j][s] = 0; }

    const int segA[3] = {0, 256, 0};
    const int segB[3] = {0, 0, 256};

    for (int it = 0; it < 7; ++it) {
        const int t0 = (rg * 7 + it) * 128;
        f32x16 acc[2][2];
#pragma unroll
        for (int i = 0; i < 2; ++i)
#pragma unroll
            for (int j = 0; j < 2; ++j) acc[i][j] = (f32x16)0.0f;

        for (int cc = 0; cc < 12; ++cc) {
            const int seg = cc >> 2, k64 = (cc & 3) * 64;
            const int aoff = segA[seg] + k64 + skk;
            const int boff = segB[seg] + k64 + skk;
#pragma unroll
            for (int p = 0; p < 4; ++p)
                async16(Xb + (size_t)(t0 + srow + 32 * p) * 512 + aoff,
                        smem + wid * 1024 + p * 4096);
#pragma unroll
            for (int p = 0; p < 4; ++p)
                async16(Xb + (size_t)(j0 + srow + 32 * p) * 512 + boff,
                        smem + 16384 + wid * 1024 + p * 4096);
            __syncthreads();
#pragma unroll
            for (int ks = 0; ks < 4; ++ks) {
                const int up = ((2 * ks + h) ^ rsw) * 8;   // swizzled unit, halves
                half8 av[2], bv[2];
#pragma unroll
                for (int i = 0; i < 2; ++i)
                    av[i] = *(const half8*)(As + (wr + 32 * i + l31) * 64 + up);
#pragma unroll
                for (int j = 0; j < 2; ++j)
                    bv[j] = *(const half8*)(Bs + (wc + 32 * j + l31) * 64 + up);
#pragma unroll
                for (int i = 0; i < 2; ++i)
#pragma unroll
                    for (int j = 0; j < 2; ++j)
                        acc[i][j] = __builtin_amdgcn_mfma_f32_32x32x16_f16(av[i], bv[j], acc[i][j], 0, 0, 0);
            }
            __syncthreads();
        }
        // epilogue: key = up * rinv[row]; mask same-frame; private top-5
        // C layout: col = lane&31, row = (reg&3) + 8*(reg>>2) + 4*(lane>>5)
#pragma unroll
        for (int i = 0; i < 2; ++i) {
            const int tb0 = t0 + wr + 32 * i;
#pragma unroll
            for (int g = 0; g < 4; ++g) {
                const int rb = tb0 + 8 * g + 4 * h;
                const f32x4 r4 = *(const f32x4*)(rv + rb);
#pragma unroll
                for (int rr = 0; rr < 4; ++rr) {
                    const int t = rb + rr;
                    const int ft = t / HW;
                    const int reg = 4 * g + rr;
#pragma unroll
                    for (int j = 0; j < 2; ++j) {
                        const float key = acc[i][j][reg] * r4[rr];
                        if (ft != fj[j]) ins5(key, t, tv[j], ti[j]);
                    }
                }
            }
        }
    }

    // merge: per column (128), 4 contributor slots (2 wave-rows x 2 lane-halves) x 5
    float* Mv = (float*)smem;                        // [128][20] floats = 10KB
    unsigned short* Mi = (unsigned short*)(smem + 10240);   // [128][20] ushort = 5KB
    const int slot = (wid >> 1) * 2 + h;
#pragma unroll
    for (int j = 0; j < 2; ++j) {
        const int c128 = wc + 32 * j + l31;
#pragma unroll
        for (int s = 0; s < TOPK; ++s) {
            Mv[(c128 * 4 + slot) * TOPK + s] = tv[j][s];
            Mi[(c128 * 4 + slot) * TOPK + s] = (unsigned short)ti[j][s];
        }
    }
    __syncthreads();
    if (tid < 128) {
        float bv5[TOPK]; int bi5[TOPK];
#pragma unroll
        for (int s = 0; s < TOPK; ++s) { bv5[s] = -FLT_MAX; bi5[s] = 0; }
        for (int s = 0; s < 20; ++s) ins5(Mv[tid * 20 + s], (int)Mi[tid * 20 + s], bv5, bi5);
        const size_t base = ((bbase + j0 + tid) * 7 + rg) * TOPK;
#pragma unroll
        for (int s = 0; s < TOPK; ++s) { pval[base + s] = bv5[s]; pidx[base + s] = bi5[s]; }
    }
}

// ------------------------------------------------- 3. merge row-group partials
__global__ __launch_bounds__(256)
void merge_topk_kernel(const float* __restrict__ pval, const int* __restrict__ pidx,
                       int* __restrict__ idx5) {
    const int gid = blockIdx.x * 256 + threadIdx.x;   // 25088 columns
    float bv5[TOPK]; int bi5[TOPK];
#pragma unroll
    for (int s = 0; s < TOPK; ++s) { bv5[s] = -FLT_MAX; bi5[s] = 0; }
    const float* pv = pval + (size_t)gid * 35;
    const int* pi = pidx + (size_t)gid * 35;
    for (int s = 0; s < 35; ++s) ins5(pv[s], pi[s], bv5, bi5);
    int* op = idx5 + (size_t)gid * TOPK;
#pragma unroll
    for (int s = 0; s < TOPK; ++s) op[s] = bi5[s];
}

// ------------------------------------------------- 4. gather (from f16 pair) + max -> y f16 + BN partials
__global__ __launch_bounds__(256)
void gather_bn_kernel(const f16* __restrict__ Xs, const int* __restrict__ idx5,
                      f16* __restrict__ yf, float* __restrict__ partial) {
    __shared__ float ls[2][4][256];
    const int tid = threadIdx.x;
    const int wid = tid >> 6, lane = tid & 63;
    const int row0 = blockIdx.x * 32 + wid * 8;
    float s1x = 0, s1y = 0, s1z = 0, s1w = 0;
    float s2x = 0, s2y = 0, s2z = 0, s2w = 0;
    for (int rr = 0; rr < 8; ++rr) {
        const int row = row0 + rr;
        const int b = row / THW;
        const int* id = idx5 + (size_t)row * TOPK;
        const f16* base = Xs + (size_t)b * THW * 512;
        float4 m = make_float4(-FLT_MAX, -FLT_MAX, -FLT_MAX, -FLT_MAX);
#pragma unroll
        for (int i = 0; i < TOPK; ++i) {
            const f16* rp = base + (size_t)id[i] * 512 + lane * 4;
            const half4 h = *(const half4*)rp;
            const half4 l = *(const half4*)(rp + 256);
            m.x = fmaxf(m.x, (float)h.x + (float)l.x);
            m.y = fmaxf(m.y, (float)h.y + (float)l.y);
            m.z = fmaxf(m.z, (float)h.z + (float)l.z);
            m.w = fmaxf(m.w, (float)h.w + (float)l.w);
        }
        half4 ym; ym.x = (f16)m.x; ym.y = (f16)m.y; ym.z = (f16)m.z; ym.w = (f16)m.w;
        *(half4*)(yf + (size_t)row * CCH + lane * 4) = ym;
        s1x += m.x; s1y += m.y; s1z += m.z; s1w += m.w;
        s2x += m.x * m.x; s2y += m.y * m.y; s2z += m.z * m.z; s2w += m.w * m.w;
    }
    *(float4*)&ls[0][wid][lane * 4] = make_float4(s1x, s1y, s1z, s1w);
    *(float4*)&ls[1][wid][lane * 4] = make_float4(s2x, s2y, s2z, s2w);
    __syncthreads();
    const float a  = ls[0][0][tid] + ls[0][1][tid] + ls[0][2][tid] + ls[0][3][tid];
    const float b2 = ls[1][0][tid] + ls[1][1][tid] + ls[1][2][tid] + ls[1][3][tid];
    partial[(size_t)blockIdx.x * 512 + tid] = a;
    partial[(size_t)blockIdx.x * 512 + 256 + tid] = b2;
}

// ------------------------------------------------- 5. BN finalize -> scale/shift
__global__ __launch_bounds__(256)
void bn_final_kernel(const float* __restrict__ partial, const float* __restrict__ gamma,
                     const float* __restrict__ beta, float* __restrict__ ab) {
    const int c = blockIdx.x;
    const int tid = threadIdx.x;
    float s1 = 0, s2 = 0;
    for (int p = tid; p < 784; p += 256) {
        s1 += partial[(size_t)p * 512 + c];
        s2 += partial[(size_t)p * 512 + 256 + c];
    }
    __shared__ float r1[256], r2[256];
    r1[tid] = s1; r2[tid] = s2;
    __syncthreads();
    for (int off = 128; off > 0; off >>= 1) {
        if (tid < off) { r1[tid] += r1[tid + off]; r2[tid] += r2[tid + off]; }
        __syncthreads();
    }
    if (tid == 0) {
        const float inv_n = 1.0f / 25088.0f;
        const float mean = r1[0] * inv_n;
        const float var  = r2[0] * inv_n - mean * mean;
        const float a = gamma[c] / sqrtf(var + 1e-5f);
        ab[c] = a;
        ab[256 + c] = beta[c] - mean * a;
    }
}

// ------------------------------------------------- 6. relu(BN) -> 1x1 conv (f16 MFMA) + identity
__global__ __launch_bounds__(256, 2)
void conv_f16_kernel(const f16* __restrict__ yf, const float* __restrict__ w,
                     const float* __restrict__ ab, const float* __restrict__ cb,
                     const float* __restrict__ x, float* __restrict__ out) {
    __shared__ __align__(16) f16 smem[2 * 128 * 64];   // 32 KB
    f16* As = smem;
    f16* Ws = smem + 8192;

    const int tid = threadIdx.x;
    const int lane = tid & 63, wid = tid >> 6;
    const int wr = (wid >> 1) * 64, wc = (wid & 1) * 64;
    const int lm = lane & 15, q = lane >> 4;
    const int lm7 = lm & 7;
    const int R0 = blockIdx.x * 128;
    const int o0 = blockIdx.y * 128;
    const int g8 = (tid & 7) * 8;
    const int sr = tid >> 3;

    f32x4 acc[4][4];
#pragma unroll
    for (int i = 0; i < 4; ++i)
#pragma unroll
        for (int j = 0; j < 4; ++j) acc[i][j] = (f32x4)0.0f;

    float cbv[4];
#pragma unroll
    for (int j = 0; j < 4; ++j) cbv[j] = cb[o0 + wc + 16 * j + lm];

    for (int kc = 0; kc < CCH; kc += 64) {
        const int cbase = kc + g8;
        const float4 sa0 = *(const float4*)(ab + cbase);
        const float4 sa1 = *(const float4*)(ab + cbase + 4);
        const float4 sb0 = *(const float4*)(ab + 256 + cbase);
        const float4 sb1 = *(const float4*)(ab + 256 + cbase + 4);
#pragma unroll
        for (int p = 0; p < 4; ++p) {
            const int r = sr + 32 * p;
            const half8 hv = *(const half8*)(yf + (size_t)(R0 + r) * CCH + cbase);
            half8 z;
            z[0] = (f16)fmaxf(fmaf((float)hv[0], sa0.x, sb0.x), 0.0f);
            z[1] = (f16)fmaxf(fmaf((float)hv[1], sa0.y, sb0.y), 0.0f);
            z[2] = (f16)fmaxf(fmaf((float)hv[2], sa0.z, sb0.z), 0.0f);
            z[3] = (f16)fmaxf(fmaf((float)hv[3], sa0.w, sb0.w), 0.0f);
            z[4] = (f16)fmaxf(fmaf((float)hv[4], sa1.x, sb1.x), 0.0f);
            z[5] = (f16)fmaxf(fmaf((float)hv[5], sa1.y, sb1.y), 0.0f);
            z[6] = (f16)fmaxf(fmaf((float)hv[6], sa1.z, sb1.z), 0.0f);
            z[7] = (f16)fmaxf(fmaf((float)hv[7], sa1.w, sb1.w), 0.0f);
            *(half8*)(As + r * 64 + (((tid & 7) ^ (r & 7)) * 8)) = z;
        }
#pragma unroll
        for (int p = 0; p < 4; ++p) {
            const int ol = sr + 32 * p;
            const float4 w0 = *(const float4*)(w + (size_t)(o0 + ol) * CCH + cbase);
            const float4 w1 = *(const float4*)(w + (size_t)(o0 + ol) * CCH + cbase + 4);
            half8 z;
            z[0] = (f16)w0.x; z[1] = (f16)w0.y; z[2] = (f16)w0.z; z[3] = (f16)w0.w;
            z[4] = (f16)w1.x; z[5] = (f16)w1.y; z[6] = (f16)w1.z; z[7] = (f16)w1.w;
            *(half8*)(Ws + ol * 64 + (((tid & 7) ^ (ol & 7)) * 8)) = z;
        }
        __syncthreads();
#pragma unroll
        for (int ks = 0; ks < 2; ++ks) {
            const int ku = (((4 * ks + q) ^ lm7) * 8);
            half8 av[4], bv[4];
#pragma unroll
            for (int i = 0; i < 4; ++i)
                av[i] = *(const half8*)(As + (wr + 16 * i + lm) * 64 + ku);
#pragma unroll
            for (int j = 0; j < 4; ++j)
                bv[j] = *(const half8*)(Ws + (wc + 16 * j + lm) * 64 + ku);
#pragma unroll
            for (int i = 0; i < 4; ++i)
#pragma unroll
                for (int j = 0; j < 4; ++j)
                    acc[i][j] = __builtin_amdgcn_mfma_f32_16x16x32_f16(av[i], bv[j], acc[i][j], 0, 0, 0);
        }
        __syncthreads();
    }
#pragma unroll
    for (int i = 0; i < 4; ++i) {
#pragma unroll
        for (int reg = 0; reg < 4; ++reg) {
            const int R = R0 + wr + 16 * i + 4 * q + reg;
            const int bs = R / HW;
            const int hw = R - bs * HW;
#pragma unroll
            for (int j = 0; j < 4; ++j) {
                const int o = o0 + wc + 16 * j + lm;
                const size_t oi = ((size_t)bs * CCH + o) * HW + hw;
                out[oi] = acc[i][j][reg] + cbv[j] + x[oi];
            }
        }
    }
}

// ------------------------------------------------- launch
extern "C" void kernel_launch(void* const* d_in, const int* in_sizes, int n_in,
                              void* d_out, int out_size, void* d_ws, size_t ws_size,
                              hipStream_t stream) {
    const float* x      = (const float*)d_in[0];
    const float* gamma  = (const float*)d_in[1];
    const float* beta   = (const float*)d_in[2];
    const float* conv_w = (const float*)d_in[3];
    const float* conv_b = (const float*)d_in[4];
    float* out = (float*)d_out;

    float* ws = (float*)d_ws;
    f16*   Xsp  = (f16*)ws;                            // [25088][512] halves = 6,422,528 f
    f16*   yf   = (f16*)(ws + 6422528);                // [25088][256] halves = 3,211,264 f
    float* rinv = ws + 9633792;                        // 25,088
    float* part = ws + 9658880;                        // 401,408
    float* ab   = ws + 10060288;                       // 512
    int*   idx5 = (int*)(ws + 10060800);               // 125,440 ints
    float* pval = ws + 10186240;                       // 25088*35 = 878,080
    int*   pidx = (int*)(ws + 11064320);               // 878,080 ints
    // total = 11,942,400 floats = 47.8 MB

    transpose_norm_split_kernel<<<dim3(32, 25), 256, 0, stream>>>(x, Xsp, rinv);
    gram_mfma_kernel<<<dim3(49, 7, B_), 256, 0, stream>>>(Xsp, rinv, pval, pidx);
    merge_topk_kernel<<<98, 256, 0, stream>>>(pval, pidx, idx5);
    gather_bn_kernel<<<NROWS / 32, 256, 0, stream>>>(Xsp, idx5, yf, part);
    bn_final_kernel<<<256, 256, 0, stream>>>(part, gamma, beta, ab);
    conv_f16_kernel<<<dim3(NROWS / 128, 2), 256, 0, stream>>>(yf, conv_w, ab, conv_b, x, out);
}

// Round 8
// 576.390 us; speedup vs baseline: 1.2187x; 1.2187x over previous
//
#include <hip/hip_runtime.h>
#include <cfloat>

#define B_    4
#define SNIP  8
#define CCH   256
#define HW    784
#define THW   6272      // SNIP*HW
#define NROWS 25088     // B_*THW
#define TOPK  5

typedef _Float16 f16;
typedef f16   half8 __attribute__((ext_vector_type(8)));
typedef f16   half4 __attribute__((ext_vector_type(4)));
typedef float f32x4 __attribute__((ext_vector_type(4)));

// ---------------------------------------------------------------- utilities
__device__ __forceinline__ void ins5(float key, int idx, float tv[TOPK], int ti[TOPK]) {
    if (key > tv[4]) {
        if (key > tv[2]) {
            if (key > tv[1]) {
                tv[4] = tv[3]; ti[4] = ti[3];
                tv[3] = tv[2]; ti[3] = ti[2];
                tv[2] = tv[1]; ti[2] = ti[1];
                if (key > tv[0]) { tv[1] = tv[0]; ti[1] = ti[0]; tv[0] = key; ti[0] = idx; }
                else             { tv[1] = key;  ti[1] = idx; }
            } else {
                tv[4] = tv[3]; ti[4] = ti[3];
                tv[3] = tv[2]; ti[3] = ti[2];
                tv[2] = key;   ti[2] = idx;
            }
        } else {
            if (key > tv[3]) { tv[4] = tv[3]; ti[4] = ti[3]; tv[3] = key; ti[3] = idx; }
            else             { tv[4] = key;  ti[4] = idx; }
        }
    }
}

__device__ __forceinline__ void async16(const void* g, void* l) {
    __builtin_amdgcn_global_load_lds(
        (const __attribute__((address_space(1))) void*)g,
        (__attribute__((address_space(3))) void*)l, 16, 0, 0);
}

// ------------------------------------------------- 1. fused transpose + rownorm + f16 split
__global__ __launch_bounds__(256)
void transpose_norm_split_kernel(const float* __restrict__ x, f16* __restrict__ Xs,
                                 float* __restrict__ rinv) {
    __shared__ float T[256][33];
    const int bs = blockIdx.x;
    const int p0 = blockIdx.y * 32;
    const int b = bs >> 3, f = bs & 7;
    const int tid = threadIdx.x;

    const int pl = tid & 31, ch = tid >> 5;
    const int p = p0 + pl;
    if (p < HW) {
#pragma unroll
        for (int cc = 0; cc < 32; ++cc) {
            const int c = cc * 8 + ch;
            T[c][pl] = x[((size_t)bs * CCH + c) * HW + p];
        }
    }
    __syncthreads();

    const int rloc = tid >> 3, k = tid & 7;
    const int gp = p0 + rloc;
    const size_t trow = (size_t)b * THW + (size_t)f * HW + gp;

    float s = 0.0f;
    if (gp < HW) {
#pragma unroll
        for (int j = 0; j < 32; ++j) {
            const float v = T[k * 32 + j][rloc];
            s += v * v;
        }
    }
    s += __shfl_xor(s, 1, 64);
    s += __shfl_xor(s, 2, 64);
    s += __shfl_xor(s, 4, 64);
    if (k == 0 && gp < HW) rinv[trow] = 1.0f / sqrtf(s);

    if (gp < HW) {
#pragma unroll
        for (int q = 0; q < 4; ++q) {
            half8 hv, lv;
#pragma unroll
            for (int j = 0; j < 8; ++j) {
                const float v = T[k * 32 + q * 8 + j][rloc];
                const f16 h = (f16)v;
                hv[j] = h;
                lv[j] = (f16)(v - (float)h);
            }
            *(half8*)(Xs + trow * 512 + k * 32 + q * 8) = hv;
            *(half8*)(Xs + trow * 512 + 256 + k * 32 + q * 8) = lv;
        }
    }
}

// ------------------------------------------------- 2. MFMA gram + partial top-5
// grid (49, 7, 4). Per block: 128-col block, 7 row-tiles of 128.
// Per 32-real-K chunk: stage A-row=[hi32|lo32], B-row=[hi32|lo32] (128B rows,
// XOR-8 unit swizzle, identical geometry to the measured r6 kernel), then
// compute ah*bh + al*bh + ah*bl from one staging: 48 MFMA / 32KB staged.
__global__ __launch_bounds__(256, 2)
void gram_mfma_kernel(const f16* __restrict__ Xs, const float* __restrict__ rinv,
                      float* __restrict__ pval, int* __restrict__ pidx) {
    __shared__ __align__(16) char smem[32768];   // staging 32KB | merge 30KB (reused)
    f16* As = (f16*)smem;                 // [128][64] halves, unit-swizzled
    f16* Bs = As + 8192;

    const int tid = threadIdx.x;
    const int lane = tid & 63, wid = tid >> 6;
    const int wr = (wid >> 1) * 64, wc = (wid & 1) * 64;
    const int lm = lane & 15, q = lane >> 4;
    const int lm7 = lm & 7;
    const int b = blockIdx.z;
    const int j0 = blockIdx.x * 128;
    const int rg = blockIdx.y;
    const size_t bbase = (size_t)b * THW;
    const f16* Xb = Xs + bbase * 512;
    const float* rv = rinv + bbase;

    // staging lane map: LDS slot (srow, tid&7) holds global unit u_g = (tid&7)^(srow&7);
    // u_g<4 -> hi plane, u_g>=4 -> lo plane (+256 halves)
    const int srow = tid >> 3;
    const int u_g = (tid & 7) ^ (srow & 7);
    const int skk = (u_g >> 2) * 256 + (u_g & 3) * 8;   // halves within row

    int fj[4];
#pragma unroll
    for (int j = 0; j < 4; ++j) fj[j] = (j0 + wc + 16 * j + lm) / HW;

    float tv[4][TOPK];
    int   ti[4][TOPK];
#pragma unroll
    for (int j = 0; j < 4; ++j)
#pragma unroll
        for (int s = 0; s < TOPK; ++s) { tv[j][s] = -FLT_MAX; ti[j][s] = 0; }

    const int uh = (q ^ lm7) * 8;        // hi-unit slot (halves); lo = uh ^ 32

    for (int it = 0; it < 7; ++it) {
        const int t0 = (rg * 7 + it) * 128;
        f32x4 acc[4][4];
#pragma unroll
        for (int i = 0; i < 4; ++i)
#pragma unroll
            for (int j = 0; j < 4; ++j) acc[i][j] = (f32x4)0.0f;

        for (int cc = 0; cc < 8; ++cc) {
            const int koff = cc * 32 + skk;
#pragma unroll
            for (int p = 0; p < 4; ++p)
                async16(Xb + (size_t)(t0 + srow + 32 * p) * 512 + koff,
                        smem + wid * 1024 + p * 4096);
#pragma unroll
            for (int p = 0; p < 4; ++p)
                async16(Xb + (size_t)(j0 + srow + 32 * p) * 512 + koff,
                        smem + 16384 + wid * 1024 + p * 4096);
            __syncthreads();
            {
                half8 ah[4], bh[4], al[4], bl[4];
#pragma unroll
                for (int i = 0; i < 4; ++i)
                    ah[i] = *(const half8*)(As + (wr + 16 * i + lm) * 64 + uh);
#pragma unroll
                for (int j = 0; j < 4; ++j)
                    bh[j] = *(const half8*)(Bs + (wc + 16 * j + lm) * 64 + uh);
#pragma unroll
                for (int i = 0; i < 4; ++i)
#pragma unroll
                    for (int j = 0; j < 4; ++j)
                        acc[i][j] = __builtin_amdgcn_mfma_f32_16x16x32_f16(ah[i], bh[j], acc[i][j], 0, 0, 0);
#pragma unroll
                for (int i = 0; i < 4; ++i)
                    al[i] = *(const half8*)(As + (wr + 16 * i + lm) * 64 + (uh ^ 32));
#pragma unroll
                for (int i = 0; i < 4; ++i)
#pragma unroll
                    for (int j = 0; j < 4; ++j)
                        acc[i][j] = __builtin_amdgcn_mfma_f32_16x16x32_f16(al[i], bh[j], acc[i][j], 0, 0, 0);
#pragma unroll
                for (int j = 0; j < 4; ++j)
                    bl[j] = *(const half8*)(Bs + (wc + 16 * j + lm) * 64 + (uh ^ 32));
#pragma unroll
                for (int i = 0; i < 4; ++i)
#pragma unroll
                    for (int j = 0; j < 4; ++j)
                        acc[i][j] = __builtin_amdgcn_mfma_f32_16x16x32_f16(ah[i], bl[j], acc[i][j], 0, 0, 0);
            }
            __syncthreads();
        }
        // epilogue: key = up * rinv[row]; mask same-frame; private top-5
#pragma unroll
        for (int i = 0; i < 4; ++i) {
            const int tb = t0 + wr + 16 * i + 4 * q;
            const f32x4 r4 = *(const f32x4*)(rv + tb);
#pragma unroll
            for (int reg = 0; reg < 4; ++reg) {
                const int t = tb + reg;
                const int ft = t / HW;
#pragma unroll
                for (int j = 0; j < 4; ++j) {
                    const float key = acc[i][j][reg] * r4[reg];
                    if (ft != fj[j]) ins5(key, t, tv[j], ti[j]);
                }
            }
        }
    }

    // merge: per column (128), 8 contributor slots (2 wave-pairs x 4 q) x 5 entries
    __syncthreads();
    float* Mv = (float*)smem;                        // [128][40] floats = 20KB
    unsigned short* Mi = (unsigned short*)(smem + 20480);   // [128][40] ushort = 10KB
    const int slot = (wid >> 1) * 4 + q;
#pragma unroll
    for (int j = 0; j < 4; ++j) {
        const int c128 = wc + 16 * j + lm;
#pragma unroll
        for (int s = 0; s < TOPK; ++s) {
            Mv[(c128 * 8 + slot) * TOPK + s] = tv[j][s];
            Mi[(c128 * 8 + slot) * TOPK + s] = (unsigned short)ti[j][s];
        }
    }
    __syncthreads();
    if (tid < 128) {
        float bv5[TOPK]; int bi5[TOPK];
#pragma unroll
        for (int s = 0; s < TOPK; ++s) { bv5[s] = -FLT_MAX; bi5[s] = 0; }
        for (int s = 0; s < 40; ++s) ins5(Mv[tid * 40 + s], (int)Mi[tid * 40 + s], bv5, bi5);
        const size_t base = ((bbase + j0 + tid) * 7 + rg) * TOPK;
#pragma unroll
        for (int s = 0; s < TOPK; ++s) { pval[base + s] = bv5[s]; pidx[base + s] = bi5[s]; }
    }
}

// ------------------------------------------------- 3. merge row-group partials
__global__ __launch_bounds__(256)
void merge_topk_kernel(const float* __restrict__ pval, const int* __restrict__ pidx,
                       int* __restrict__ idx5) {
    const int gid = blockIdx.x * 256 + threadIdx.x;   // 25088 columns
    float bv5[TOPK]; int bi5[TOPK];
#pragma unroll
    for (int s = 0; s < TOPK; ++s) { bv5[s] = -FLT_MAX; bi5[s] = 0; }
    const float* pv = pval + (size_t)gid * 35;
    const int* pi = pidx + (size_t)gid * 35;
    for (int s = 0; s < 35; ++s) ins5(pv[s], pi[s], bv5, bi5);
    int* op = idx5 + (size_t)gid * TOPK;
#pragma unroll
    for (int s = 0; s < TOPK; ++s) op[s] = bi5[s];
}

// ------------------------------------------------- 4. gather (from f16 pair) + max -> y f16 + BN partials
__global__ __launch_bounds__(256)
void gather_bn_kernel(const f16* __restrict__ Xs, const int* __restrict__ idx5,
                      f16* __restrict__ yf, float* __restrict__ partial) {
    __shared__ float ls[2][4][256];
    const int tid = threadIdx.x;
    const int wid = tid >> 6, lane = tid & 63;
    const int row0 = blockIdx.x * 32 + wid * 8;
    float s1x = 0, s1y = 0, s1z = 0, s1w = 0;
    float s2x = 0, s2y = 0, s2z = 0, s2w = 0;
    for (int rr = 0; rr < 8; ++rr) {
        const int row = row0 + rr;
        const int b = row / THW;
        const int* id = idx5 + (size_t)row * TOPK;
        const f16* base = Xs + (size_t)b * THW * 512;
        float4 m = make_float4(-FLT_MAX, -FLT_MAX, -FLT_MAX, -FLT_MAX);
#pragma unroll
        for (int i = 0; i < TOPK; ++i) {
            const f16* rp = base + (size_t)id[i] * 512 + lane * 4;
            const half4 h = *(const half4*)rp;
            const half4 l = *(const half4*)(rp + 256);
            m.x = fmaxf(m.x, (float)h.x + (float)l.x);
            m.y = fmaxf(m.y, (float)h.y + (float)l.y);
            m.z = fmaxf(m.z, (float)h.z + (float)l.z);
            m.w = fmaxf(m.w, (float)h.w + (float)l.w);
        }
        half4 ym; ym.x = (f16)m.x; ym.y = (f16)m.y; ym.z = (f16)m.z; ym.w = (f16)m.w;
        *(half4*)(yf + (size_t)row * CCH + lane * 4) = ym;
        s1x += m.x; s1y += m.y; s1z += m.z; s1w += m.w;
        s2x += m.x * m.x; s2y += m.y * m.y; s2z += m.z * m.z; s2w += m.w * m.w;
    }
    *(float4*)&ls[0][wid][lane * 4] = make_float4(s1x, s1y, s1z, s1w);
    *(float4*)&ls[1][wid][lane * 4] = make_float4(s2x, s2y, s2z, s2w);
    __syncthreads();
    const float a  = ls[0][0][tid] + ls[0][1][tid] + ls[0][2][tid] + ls[0][3][tid];
    const float b2 = ls[1][0][tid] + ls[1][1][tid] + ls[1][2][tid] + ls[1][3][tid];
    partial[(size_t)blockIdx.x * 512 + tid] = a;
    partial[(size_t)blockIdx.x * 512 + 256 + tid] = b2;
}

// ------------------------------------------------- 5. BN finalize -> scale/shift
__global__ __launch_bounds__(256)
void bn_final_kernel(const float* __restrict__ partial, const float* __restrict__ gamma,
                     const float* __restrict__ beta, float* __restrict__ ab) {
    const int c = blockIdx.x;
    const int tid = threadIdx.x;
    float s1 = 0, s2 = 0;
    for (int p = tid; p < 784; p += 256) {
        s1 += partial[(size_t)p * 512 + c];
        s2 += partial[(size_t)p * 512 + 256 + c];
    }
    __shared__ float r1[256], r2[256];
    r1[tid] = s1; r2[tid] = s2;
    __syncthreads();
    for (int off = 128; off > 0; off >>= 1) {
        if (tid < off) { r1[tid] += r1[tid + off]; r2[tid] += r2[tid + off]; }
        __syncthreads();
    }
    if (tid == 0) {
        const float inv_n = 1.0f / 25088.0f;
        const float mean = r1[0] * inv_n;
        const float var  = r2[0] * inv_n - mean * mean;
        const float a = gamma[c] / sqrtf(var + 1e-5f);
        ab[c] = a;
        ab[256 + c] = beta[c] - mean * a;
    }
}

// ------------------------------------------------- 6. relu(BN) -> 1x1 conv (f16 MFMA) + identity
__global__ __launch_bounds__(256, 2)
void conv_f16_kernel(const f16* __restrict__ yf, const float* __restrict__ w,
                     const float* __restrict__ ab, const float* __restrict__ cb,
                     const float* __restrict__ x, float* __restrict__ out) {
    __shared__ __align__(16) f16 smem[2 * 128 * 64];   // 32 KB
    f16* As = smem;
    f16* Ws = smem + 8192;

    const int tid = threadIdx.x;
    const int lane = tid & 63, wid = tid >> 6;
    const int wr = (wid >> 1) * 64, wc = (wid & 1) * 64;
    const int lm = lane & 15, q = lane >> 4;
    const int lm7 = lm & 7;
    const int R0 = blockIdx.x * 128;
    const int o0 = blockIdx.y * 128;
    const int g8 = (tid & 7) * 8;
    const int sr = tid >> 3;

    f32x4 acc[4][4];
#pragma unroll
    for (int i = 0; i < 4; ++i)
#pragma unroll
        for (int j = 0; j < 4; ++j) acc[i][j] = (f32x4)0.0f;

    float cbv[4];
#pragma unroll
    for (int j = 0; j < 4; ++j) cbv[j] = cb[o0 + wc + 16 * j + lm];

    for (int kc = 0; kc < CCH; kc += 64) {
        const int cbase = kc + g8;
        const float4 sa0 = *(const float4*)(ab + cbase);
        const float4 sa1 = *(const float4*)(ab + cbase + 4);
        const float4 sb0 = *(const float4*)(ab + 256 + cbase);
        const float4 sb1 = *(const float4*)(ab + 256 + cbase + 4);
#pragma unroll
        for (int p = 0; p < 4; ++p) {
            const int r = sr + 32 * p;
            const half8 hv = *(const half8*)(yf + (size_t)(R0 + r) * CCH + cbase);
            half8 z;
            z[0] = (f16)fmaxf(fmaf((float)hv[0], sa0.x, sb0.x), 0.0f);
            z[1] = (f16)fmaxf(fmaf((float)hv[1], sa0.y, sb0.y), 0.0f);
            z[2] = (f16)fmaxf(fmaf((float)hv[2], sa0.z, sb0.z), 0.0f);
            z[3] = (f16)fmaxf(fmaf((float)hv[3], sa0.w, sb0.w), 0.0f);
            z[4] = (f16)fmaxf(fmaf((float)hv[4], sa1.x, sb1.x), 0.0f);
            z[5] = (f16)fmaxf(fmaf((float)hv[5], sa1.y, sb1.y), 0.0f);
            z[6] = (f16)fmaxf(fmaf((float)hv[6], sa1.z, sb1.z), 0.0f);
            z[7] = (f16)fmaxf(fmaf((float)hv[7], sa1.w, sb1.w), 0.0f);
            *(half8*)(As + r * 64 + (((tid & 7) ^ (r & 7)) * 8)) = z;
        }
#pragma unroll
        for (int p = 0; p < 4; ++p) {
            const int ol = sr + 32 * p;
            const float4 w0 = *(const float4*)(w + (size_t)(o0 + ol) * CCH + cbase);
            const float4 w1 = *(const float4*)(w + (size_t)(o0 + ol) * CCH + cbase + 4);
            half8 z;
            z[0] = (f16)w0.x; z[1] = (f16)w0.y; z[2] = (f16)w0.z; z[3] = (f16)w0.w;
            z[4] = (f16)w1.x; z[5] = (f16)w1.y; z[6] = (f16)w1.z; z[7] = (f16)w1.w;
            *(half8*)(Ws + ol * 64 + (((tid & 7) ^ (ol & 7)) * 8)) = z;
        }
        __syncthreads();
#pragma unroll
        for (int ks = 0; ks < 2; ++ks) {
            const int ku = (((4 * ks + q) ^ lm7) * 8);
            half8 av[4], bv[4];
#pragma unroll
            for (int i = 0; i < 4; ++i)
                av[i] = *(const half8*)(As + (wr + 16 * i + lm) * 64 + ku);
#pragma unroll
            for (int j = 0; j < 4; ++j)
                bv[j] = *(const half8*)(Ws + (wc + 16 * j + lm) * 64 + ku);
#pragma unroll
            for (int i = 0; i < 4; ++i)
#pragma unroll
                for (int j = 0; j < 4; ++j)
                    acc[i][j] = __builtin_amdgcn_mfma_f32_16x16x32_f16(av[i], bv[j], acc[i][j], 0, 0, 0);
        }
        __syncthreads();
    }
#pragma unroll
    for (int i = 0; i < 4; ++i) {
#pragma unroll
        for (int reg = 0; reg < 4; ++reg) {
            const int R = R0 + wr + 16 * i + 4 * q + reg;
            const int bs = R / HW;
            const int hw = R - bs * HW;
#pragma unroll
            for (int j = 0; j < 4; ++j) {
                const int o = o0 + wc + 16 * j + lm;
                const size_t oi = ((size_t)bs * CCH + o) * HW + hw;
                out[oi] = acc[i][j][reg] + cbv[j] + x[oi];
            }
        }
    }
}

// ------------------------------------------------- launch
extern "C" void kernel_launch(void* const* d_in, const int* in_sizes, int n_in,
                              void* d_out, int out_size, void* d_ws, size_t ws_size,
                              hipStream_t stream) {
    const float* x      = (const float*)d_in[0];
    const float* gamma  = (const float*)d_in[1];
    const float* beta   = (const float*)d_in[2];
    const float* conv_w = (const float*)d_in[3];
    const float* conv_b = (const float*)d_in[4];
    float* out = (float*)d_out;

    float* ws = (float*)d_ws;
    f16*   Xsp  = (f16*)ws;                            // [25088][512] halves = 6,422,528 f
    f16*   yf   = (f16*)(ws + 6422528);                // [25088][256] halves = 3,211,264 f
    float* rinv = ws + 9633792;                        // 25,088
    float* part = ws + 9658880;                        // 401,408
    float* ab   = ws + 10060288;                       // 512
    int*   idx5 = (int*)(ws + 10060800);               // 125,440 ints
    float* pval = ws + 10186240;                       // 25088*35 = 878,080
    int*   pidx = (int*)(ws + 11064320);               // 878,080 ints
    // total = 11,942,400 floats = 47.8 MB

    transpose_norm_split_kernel<<<dim3(32, 25), 256, 0, stream>>>(x, Xsp, rinv);
    gram_mfma_kernel<<<dim3(49, 7, B_), 256, 0, stream>>>(Xsp, rinv, pval, pidx);
    merge_topk_kernel<<<98, 256, 0, stream>>>(pval, pidx, idx5);
    gather_bn_kernel<<<NROWS / 32, 256, 0, stream>>>(Xsp, idx5, yf, part);
    bn_final_kernel<<<256, 256, 0, stream>>>(part, gamma, beta, ab);
    conv_f16_kernel<<<dim3(NROWS / 128, 2), 256, 0, stream>>>(yf, conv_w, ab, conv_b, x, out);
}